// Round 2
// baseline (5628.389 us; speedup 1.0000x reference)
//
#include <hip/hip_runtime.h>
#include <stdint.h>

// Problem constants
#define BB   32      // batch
#define SS   512     // seq len
#define EE   256     // input dim
#define HH   256     // hidden
#define H4   1024    // 4*H
#define HC   16      // h-columns owned per workgroup
#define NG   16      // slices (WGs) per direction
#define NWG  32      // total WGs (2 directions)
#define NTHR 512     // threads per WG (8 waves)

typedef short bf16x8 __attribute__((ext_vector_type(8)));
typedef float f32x4  __attribute__((ext_vector_type(4)));
typedef unsigned short u16x4 __attribute__((ext_vector_type(4)));

// ---- old (fallback) kernel LDS offsets ----
#define O_HF  0
#define O_SF  16384
#define O_XB  32768
#define O_ZB  49152
#define O_US  57344
#define O_UH  59392
#define O_CB  61440
#define O_MB  63488
#define O_SMEM 63744

// ---- new kernel LDS offsets ----
#define N_HF  0        // blended h_t A-frags (16KB)
#define N_SF  16384    // blended s_t A-frags (16KB)
#define N_HN  32768    // h_new pre-blend A-frags (16KB)
#define N_ZB  49152    // z tiles f32 (8KB)
#define N_CB  57344    // c state f32 [32][16] (2KB)
#define N_MB  59392    // mask [2][32] f32 (256B)
#define N_SMEM 59648

__device__ __forceinline__ float bf2f(uint32_t u) {
  union { uint32_t i; float f; } v; v.i = u << 16; return v.f;
}
__device__ __forceinline__ uint32_t f2bf(float f) {
  union { float f; uint32_t i; } v; v.f = f;
  return (v.i + 0x7fffu + ((v.i >> 16) & 1u)) >> 16;
}
__device__ __forceinline__ float sigm(float x) { return 1.f / (1.f + __expf(-x)); }
__device__ __forceinline__ float tanhfast(float x) {
  float e = __expf(2.f * x);
  return 1.f - 2.f / (1.f + e);
}
// byte offset of element (batch m, k) inside a 16KB fragment region.
__device__ __forceinline__ int fragAddr(int m, int k) {
  return (((m >> 4) * 8 + (k >> 5)) << 10) + (((m & 15) + (((k >> 3) & 3) << 4)) << 4) + ((k & 7) << 1);
}
__device__ __forceinline__ f32x4 mfma16(bf16x8 a, bf16x8 b, f32x4 c) {
  return __builtin_amdgcn_mfma_f32_16x16x32_bf16(a, b, c, 0, 0, 0);
}

__global__ void init_flags(uint32_t* f) {
  int i = blockIdx.x * blockDim.x + threadIdx.x;
  if (i < 1024) f[i] = 0u;
}
__global__ void zero_words(uint32_t* p, int n) {
  int i = blockIdx.x * blockDim.x + threadIdx.x;
  if (i < n) p[i] = 0u;
}

// ============================================================================
// Pre-pass: XZ[dir][t][col][b] = (x[b,t,:] @ Wx + b)[col]  (bf16)
// grid: 256 blocks = 2 dir x 128 t-blocks (4 t each); 512 threads.
// ============================================================================
__global__ void __launch_bounds__(512)
xz_prepass(const float* __restrict__ x,
           const float* __restrict__ Wx_f, const float* __restrict__ b_f,
           const float* __restrict__ Wx_r, const float* __restrict__ b_r,
           unsigned short* __restrict__ xz) {
  __shared__ __align__(16) char smem[65536];
  const int bid = blockIdx.x;
  const int dir = bid >> 7;
  const int t0  = (bid & 127) * 4;
  const int tid = threadIdx.x;
  const int w = tid >> 6, lane = tid & 63;
  const int lr = lane & 15, lq = lane >> 4;
  const float* W  = dir ? Wx_r : Wx_f;
  const float* bv = dir ? b_r  : b_f;

  // stage A-frags for 4 timesteps
  {
    const int bm = tid >> 4, e0 = (tid & 15) * 16;
    for (int tt = 0; tt < 4; ++tt) {
      const float* xs = x + ((size_t)bm * SS + (t0 + tt)) * EE + e0;
      float xr[16];
      #pragma unroll
      for (int i = 0; i < 16; ++i) xr[i] = xs[i];
      #pragma unroll
      for (int hfi = 0; hfi < 2; ++hfi) {
        bf16x8 vv;
        #pragma unroll
        for (int i = 0; i < 8; ++i) vv[i] = (short)f2bf(xr[hfi * 8 + i]);
        *(bf16x8*)(smem + tt * 16384 + fragAddr(bm, e0 + hfi * 8)) = vv;
      }
    }
  }
  __syncthreads();

  for (int j = 0; j < 8; ++j) {
    const int col = (w * 8 + j) * 16 + lr;
    const float breg = bv[col];
    f32x4 acc[4][2];
    #pragma unroll
    for (int tt = 0; tt < 4; ++tt)
      #pragma unroll
      for (int m = 0; m < 2; ++m) {
        acc[tt][m][0] = breg; acc[tt][m][1] = breg;
        acc[tt][m][2] = breg; acc[tt][m][3] = breg;
      }
    #pragma unroll
    for (int kk = 0; kk < 8; ++kk) {
      bf16x8 bfr;
      #pragma unroll
      for (int i = 0; i < 8; ++i)
        bfr[i] = (short)f2bf(W[(size_t)(kk * 32 + lq * 8 + i) * H4 + col]);
      #pragma unroll
      for (int tt = 0; tt < 4; ++tt) {
        bf16x8 a0 = *(const bf16x8*)(smem + tt * 16384 + (kk << 10) + lane * 16);
        bf16x8 a1 = *(const bf16x8*)(smem + tt * 16384 + ((8 + kk) << 10) + lane * 16);
        acc[tt][0] = mfma16(a0, bfr, acc[tt][0]);
        acc[tt][1] = mfma16(a1, bfr, acc[tt][1]);
      }
    }
    #pragma unroll
    for (int tt = 0; tt < 4; ++tt)
      #pragma unroll
      for (int m = 0; m < 2; ++m) {
        u16x4 pk;
        #pragma unroll
        for (int i = 0; i < 4; ++i) pk[i] = (unsigned short)f2bf(acc[tt][m][i]);
        *(u16x4*)(xz + (((size_t)dir * SS + (t0 + tt)) * H4 + col) * BB + m * 16 + lq * 4) = pk;
      }
  }
}

// ============================================================================
// New persistent kernel: ONE exchange (h_new) per step; s computed full-width
// locally in every WG. 4 barriers/step.
// ============================================================================
__global__ void __launch_bounds__(NTHR)
slstm_fast(const float* __restrict__ mask,
           const float* Wh_f, const float* Ws_f,
           const float* Us_f, const float* Uh_f, const float* bs_f,
           const float* Wh_r, const float* Ws_r,
           const float* Us_r, const float* Uh_r, const float* bs_r,
           const unsigned short* __restrict__ xz,
           float* __restrict__ out,
           uint32_t* __restrict__ flags, uint32_t* __restrict__ hbufB) {
  __shared__ __align__(16) char smem[N_SMEM];

  const int bid = blockIdx.x;
  const int dir = bid >> 4;
  const int g   = bid & 15;
  const int tid = threadIdx.x;
  const int w    = tid >> 6;
  const int lane = tid & 63;
  const int lr = lane & 15, lq = lane >> 4;
  const int mt = w & 1;          // m-tile for z GEMM
  const int q  = w >> 1;         // gate

  const float* Wh = dir ? Wh_r : Wh_f;
  const float* Ws = dir ? Ws_r : Ws_f;
  const float* Us = dir ? Us_r : Us_f;
  const float* Uh = dir ? Uh_r : Uh_f;
  const float* bs = dir ? bs_r : bs_f;

  uint32_t* flagH = flags + dir * NG * 16;           // [16sl][16pad]
  uint32_t* hbufD = hbufB + dir * 2 * (NG * 256);    // [2par][16sl][256]

  // ---- preload Wh/Ws slice B-frags ----
  bf16x8 WhF[8], WsF[8];
  {
    const int col = q * HH + g * HC + lr;
    #pragma unroll
    for (int kk = 0; kk < 8; ++kk) {
      bf16x8 vh, vs;
      #pragma unroll
      for (int i = 0; i < 8; ++i) {
        int k = kk * 32 + lq * 8 + i;
        vh[i] = (short)f2bf(Wh[(size_t)k * H4 + col]);
        vs[i] = (short)f2bf(Ws[(size_t)k * H4 + col]);
      }
      WhF[kk] = vh; WsF[kk] = vs;
    }
  }
  // ---- preload FULL-WIDTH Us/Uh B-frags: wave w owns s n-tiles {2w, 2w+1} ----
  bf16x8 UsF[2][8], UhF[2][8];
  float bsreg[2];
  #pragma unroll
  for (int j = 0; j < 2; ++j) {
    const int colU = (2 * w + j) * 16 + lr;
    bsreg[j] = bs[colU];
    #pragma unroll
    for (int kk = 0; kk < 8; ++kk) {
      bf16x8 vu, vh2;
      #pragma unroll
      for (int i = 0; i < 8; ++i) {
        int k = kk * 32 + lq * 8 + i;
        vu[i]  = (short)f2bf(Us[(size_t)k * HH + colU]);
        vh2[i] = (short)f2bf(Uh[(size_t)k * HH + colU]);
      }
      UsF[j][kk] = vu; UhF[j][kk] = vh2;
    }
  }

  // ---- zero state ----
  {
    uint4* p = (uint4*)(smem);   // HF+SF = 32KB
    for (int i = tid; i < 2048; i += NTHR) p[i] = make_uint4(0u, 0u, 0u, 0u);
    float* cb = (float*)(smem + N_CB);
    for (int i = tid; i < BB * HC; i += NTHR) cb[i] = 0.f;
  }
  // ---- stage mask_0, xz_0 ----
  const int zcol = q * HH + g * HC + lr;
  const int ta0 = dir ? (SS - 1) : 0;
  if (tid < BB) ((float*)(smem + N_MB))[tid] = mask[(size_t)tid * SS + ta0];
  u16x4 xzv = *(const u16x4*)(xz + (((size_t)dir * SS + ta0) * H4 + zcol) * BB + mt * 16 + lq * 4);
  __syncthreads();

  for (int t = 0; t < SS; ++t) {
    const int par = t & 1;
    uint32_t* HbufP = hbufD + par * (NG * 256);
    const float* mb = (const float*)(smem + N_MB + par * 128);

    // ---- phase A: z GEMM (Wh,Ws) + s@Us full-width ----
    f32x4 accZ;
    accZ[0] = bf2f(xzv[0]); accZ[1] = bf2f(xzv[1]);
    accZ[2] = bf2f(xzv[2]); accZ[3] = bf2f(xzv[3]);
    f32x4 accS[2][2];
    #pragma unroll
    for (int j = 0; j < 2; ++j)
      #pragma unroll
      for (int m = 0; m < 2; ++m) { accS[j][m][0]=0.f; accS[j][m][1]=0.f; accS[j][m][2]=0.f; accS[j][m][3]=0.f; }
    #pragma unroll
    for (int kk = 0; kk < 8; ++kk) {
      bf16x8 as0 = *(const bf16x8*)(smem + N_SF + (kk << 10) + lane * 16);
      bf16x8 as1 = *(const bf16x8*)(smem + N_SF + ((8 + kk) << 10) + lane * 16);
      bf16x8 ah  = *(const bf16x8*)(smem + N_HF + ((mt * 8 + kk) << 10) + lane * 16);
      bf16x8 asz = *(const bf16x8*)(smem + N_SF + ((mt * 8 + kk) << 10) + lane * 16);
      accZ = mfma16(ah, WhF[kk], accZ);
      accZ = mfma16(asz, WsF[kk], accZ);
      #pragma unroll
      for (int j = 0; j < 2; ++j) {
        accS[j][0] = mfma16(as0, UsF[j][kk], accS[j][0]);
        accS[j][1] = mfma16(as1, UsF[j][kk], accS[j][1]);
      }
    }
    {
      float* zb = (float*)(smem + N_ZB);
      #pragma unroll
      for (int i = 0; i < 4; ++i)
        zb[(mt * 4 + q) * 256 + (lq * 4 + i) * 16 + lr] = accZ[i];
    }
    __syncthreads();   // bar1

    // ---- phase B: gates, c update, publish h_new ----
    const int bm = tid >> 4, cc = tid & 15;
    const int mtL = bm >> 4, rr = bm & 15;
    float hbl, cbl, mval;
    {
      const float* zb = (const float*)(smem + N_ZB);
      float zi = zb[(mtL * 4 + 0) * 256 + rr * 16 + cc];
      float zf = zb[(mtL * 4 + 1) * 256 + rr * 16 + cc];
      float zg = zb[(mtL * 4 + 2) * 256 + rr * 16 + cc];
      float zo = zb[(mtL * 4 + 3) * 256 + rr * 16 + cc];
      float* cb = (float*)(smem + N_CB);
      float cold = cb[tid];
      mval = mb[bm];
      float cn = sigm(zf) * cold + sigm(zi) * tanhfast(zg);
      float hnew = sigm(zo) * tanhfast(cn);
      cbl = mval * cn + (1.f - mval) * cold;
      cb[tid] = cbl;
      float hold = bf2f(*(const uint16_t*)(smem + N_HF + fragAddr(bm, g * HC + cc)));
      hbl = mval * hnew + (1.f - mval) * hold;
      uint32_t hb = f2bf(hnew);
      uint32_t pv = (uint32_t)__shfl_xor((int)hb, 1);
      if ((tid & 1) == 0) {
        uint32_t word = (hb & 0xffffu) | (pv << 16);
        __hip_atomic_store(&HbufP[g * 256 + (tid >> 1)], word,
                           __ATOMIC_RELAXED, __HIP_MEMORY_SCOPE_AGENT);
      }
    }
    __syncthreads();   // bar2
    if (tid == 0)
      __hip_atomic_store(&flagH[g * 16], (uint32_t)(t + 1),
                         __ATOMIC_RELAXED, __HIP_MEMORY_SCOPE_AGENT);

    // ---- out writes + next-step prefetch (drain during poll) ----
    const int tact = dir ? (SS - 1 - t) : t;
    {
      size_t ob = ((size_t)tact * BB + bm) * (2 * HH) + (size_t)dir * HH + g * HC + cc;
      __builtin_nontemporal_store(hbl, &out[ob]);
      __builtin_nontemporal_store(cbl, &out[ob + 8388608]);
    }
    if (t + 1 < SS) {
      const int ta = dir ? (SS - 2 - t) : (t + 1);
      xzv = *(const u16x4*)(xz + (((size_t)dir * SS + ta) * H4 + zcol) * BB + mt * 16 + lq * 4);
      if (tid < BB) {
        float mreg = mask[(size_t)tid * SS + ta];
        ((float*)(smem + N_MB + (par ^ 1) * 128))[tid] = mreg;
      }
    }

    // ---- phase C: poll + consume h slices -> HN (pre-blend) + HF (blended) ----
    #pragma unroll
    for (int ssl = 0; ssl < 2; ++ssl) {
      const int sl = w + ssl * 8;
      if (lane == 0) {
        while (__hip_atomic_load(&flagH[sl * 16], __ATOMIC_RELAXED,
                                 __HIP_MEMORY_SCOPE_AGENT) < (uint32_t)(t + 1)) {}
      }
      const uint32_t* src = HbufP + sl * 256;
      #pragma unroll
      for (int ww = 0; ww < 4; ++ww) {
        const int word = ww * 64 + lane;
        uint32_t v = __hip_atomic_load(&src[word], __ATOMIC_RELAXED, __HIP_MEMORY_SCOPE_AGENT);
        const int mrow = word >> 3, c0 = (word & 7) * 2;
        const int fa = fragAddr(mrow, sl * HC + c0);
        *(uint32_t*)(smem + N_HN + fa) = v;
        uint32_t ov = *(const uint32_t*)(smem + N_HF + fa);
        float mv = mb[mrow];
        float b0 = mv * bf2f(v & 0xffffu) + (1.f - mv) * bf2f(ov & 0xffffu);
        float b1 = mv * bf2f(v >> 16)     + (1.f - mv) * bf2f(ov >> 16);
        *(uint32_t*)(smem + N_HF + fa) = (f2bf(b0) & 0xffffu) | (f2bf(b1) << 16);
      }
    }
    __syncthreads();   // bar3

    // ---- phase D: h_new@Uh full-width onto accS; s_new; blend SF; s_out ----
    #pragma unroll
    for (int kk = 0; kk < 8; ++kk) {
      bf16x8 an0 = *(const bf16x8*)(smem + N_HN + (kk << 10) + lane * 16);
      bf16x8 an1 = *(const bf16x8*)(smem + N_HN + ((8 + kk) << 10) + lane * 16);
      #pragma unroll
      for (int j = 0; j < 2; ++j) {
        accS[j][0] = mfma16(an0, UhF[j][kk], accS[j][0]);
        accS[j][1] = mfma16(an1, UhF[j][kk], accS[j][1]);
      }
    }
    #pragma unroll
    for (int j = 0; j < 2; ++j) {
      const int scol = (2 * w + j) * 16 + lr;
      const bool own_ntile = ((2 * w + j) == g);
      #pragma unroll
      for (int mti = 0; mti < 2; ++mti) {
        #pragma unroll
        for (int i = 0; i < 4; ++i) {
          const int m = mti * 16 + lq * 4 + i;
          float sn = tanhfast(accS[j][mti][i] + bsreg[j]);
          float mv = mb[m];
          uint32_t sb = f2bf(sn);
          uint32_t pvs = (uint32_t)__shfl_xor((int)sb, 1);
          if (own_ntile) {   // wave-uniform: write this slice's s_out (read old BEFORE write)
            float sold = bf2f(*(const uint16_t*)(smem + N_SF + fragAddr(m, scol)));
            float sbl = mv * sn + (1.f - mv) * sold;
            __builtin_nontemporal_store(
                sbl, &out[((size_t)tact * BB + m) * (2 * HH) + (size_t)dir * HH + scol - ((2*w+j)*16) + g * HC + 16777216]);
          }
          if ((lr & 1) == 0) {
            const int fa = fragAddr(m, scol);   // scol even here
            uint32_t ov = *(const uint32_t*)(smem + N_SF + fa);
            float b0 = mv * bf2f(sb & 0xffffu)  + (1.f - mv) * bf2f(ov & 0xffffu);
            float b1 = mv * bf2f(pvs & 0xffffu) + (1.f - mv) * bf2f(ov >> 16);
            *(uint32_t*)(smem + N_SF + fa) = (f2bf(b0) & 0xffffu) | (f2bf(b1) << 16);
          }
        }
      }
    }
    __syncthreads();   // bar4
  }
}

// ============================================================================
// Fallback: proven round-1 kernel (2 exchanges/step), used if ws too small.
// ============================================================================
__global__ void __launch_bounds__(NTHR)
slstm_persistent(const float* __restrict__ x, const float* __restrict__ mask,
                 const float* Wx_f, const float* Wh_f, const float* Ws_f, const float* b_f,
                 const float* Us_f, const float* Uh_f, const float* bs_f,
                 const float* Wx_r, const float* Wh_r, const float* Ws_r, const float* b_r,
                 const float* Us_r, const float* Uh_r, const float* bs_r,
                 float* __restrict__ out, uint32_t* __restrict__ wsbase) {
  __shared__ __align__(16) char smem[O_SMEM];

  const int bid = blockIdx.x;
  const int dir = bid >> 4;
  const int g   = bid & 15;
  const int tid = threadIdx.x;
  const int w    = tid >> 6;
  const int lane = tid & 63;
  const int lr = lane & 15, lq = lane >> 4;
  const int mt = w & 1;
  const int q  = w >> 1;

  const float* Wx = dir ? Wx_r : Wx_f;
  const float* Wh = dir ? Wh_r : Wh_f;
  const float* Ws = dir ? Ws_r : Ws_f;
  const float* bv = dir ? b_r  : b_f;
  const float* Us = dir ? Us_r : Us_f;
  const float* Uh = dir ? Uh_r : Uh_f;
  const float* bs = dir ? bs_r : bs_f;

  uint32_t* flags = wsbase;
  uint32_t* hbufB = wsbase + 1024;
  uint32_t* sbufB = wsbase + 1024 + 16384;
  uint32_t* flagH = flags + (dir * 2 + 0) * NG * 16;
  uint32_t* flagS = flags + (dir * 2 + 1) * NG * 16;

  bf16x8 WxF[8], WhF[8], WsF[8], UF[8];
  {
    const int col = q * HH + g * HC + lr;
    #pragma unroll
    for (int kk = 0; kk < 8; ++kk) {
      bf16x8 vx, vh, vs;
      #pragma unroll
      for (int i = 0; i < 8; ++i) {
        int k = kk * 32 + lq * 8 + i;
        vx[i] = (short)f2bf(Wx[k * H4 + col]);
        vh[i] = (short)f2bf(Wh[k * H4 + col]);
        vs[i] = (short)f2bf(Ws[k * H4 + col]);
      }
      WxF[kk] = vx; WhF[kk] = vh; WsF[kk] = vs;
    }
  }
  if (w < 4) {
    const float* U = (w < 2) ? Us : Uh;
    const int colU = g * HC + lr;
    #pragma unroll
    for (int kk = 0; kk < 8; ++kk) {
      bf16x8 vu;
      #pragma unroll
      for (int i = 0; i < 8; ++i) {
        int k = kk * 32 + lq * 8 + i;
        vu[i] = (short)f2bf(U[k * HH + colU]);
      }
      UF[kk] = vu;
    }
  }
  const float breg  = bv[q * HH + g * HC + lr];
  const float bsreg = bs[g * HC + (tid & 15)];

  {
    uint4* p = (uint4*)(smem);
    for (int i = tid; i < 2048; i += NTHR) p[i] = make_uint4(0u, 0u, 0u, 0u);
    float* cb = (float*)(smem + O_CB);
    for (int i = tid; i < BB * HC; i += NTHR) cb[i] = 0.f;
  }
  {
    const int ta = dir ? (SS - 1) : 0;
    const int bm = tid >> 4, e0 = (tid & 15) * 16;
    const float* xs = x + ((size_t)bm * SS + ta) * EE + e0;
    float xr0[16];
    #pragma unroll
    for (int i = 0; i < 16; ++i) xr0[i] = xs[i];
    #pragma unroll
    for (int hfi = 0; hfi < 2; ++hfi) {
      bf16x8 vv;
      #pragma unroll
      for (int i = 0; i < 8; ++i) vv[i] = (short)f2bf(xr0[hfi * 8 + i]);
      *(bf16x8*)(smem + O_XB + fragAddr(bm, e0 + hfi * 8)) = vv;
    }
    if (tid < BB) ((float*)(smem + O_MB))[tid] = mask[(size_t)tid * SS + ta];
  }
  __syncthreads();

  for (int t = 0; t < SS; ++t) {
    const int par = t & 1;
    uint32_t* HbufP = hbufB + (dir * 2 + par) * (NG * 256);
    uint32_t* SbufP = sbufB + (dir * 2 + par) * (NG * 256);
    const float* mb = (const float*)(smem + O_MB + par * 128);

    f32x4 accZ; accZ[0] = breg; accZ[1] = breg; accZ[2] = breg; accZ[3] = breg;
    f32x4 accU = {0.f, 0.f, 0.f, 0.f};
    #pragma unroll
    for (int kk = 0; kk < 8; ++kk) {
      const int fb = ((mt * 8 + kk) << 10) + lane * 16;
      bf16x8 ah = *(const bf16x8*)(smem + O_HF + fb);
      bf16x8 as = *(const bf16x8*)(smem + O_SF + fb);
      bf16x8 ax = *(const bf16x8*)(smem + O_XB + fb);
      accZ = mfma16(ax, WxF[kk], accZ);
      accZ = mfma16(ah, WhF[kk], accZ);
      accZ = mfma16(as, WsF[kk], accZ);
      if (w < 2) accU = mfma16(as, UF[kk], accU);
    }

    float xr[16]; float mreg = 0.f;
    if (t + 1 < SS) {
      const int ta = dir ? (SS - 2 - t) : (t + 1);
      const int bm = tid >> 4, e0 = (tid & 15) * 16;
      const float* xs = x + ((size_t)bm * SS + ta) * EE + e0;
      #pragma unroll
      for (int i = 0; i < 16; ++i) xr[i] = xs[i];
      if (tid < BB) mreg = mask[(size_t)tid * SS + ta];
    }

    {
      float* zb = (float*)(smem + O_ZB);
      #pragma unroll
      for (int i = 0; i < 4; ++i)
        zb[(mt * 4 + q) * 256 + (lq * 4 + i) * 16 + lr] = accZ[i];
      if (w < 2) {
        float* ub = (float*)(smem + O_US);
        #pragma unroll
        for (int i = 0; i < 4; ++i)
          ub[mt * 256 + (lq * 4 + i) * 16 + lr] = accU[i];
      }
    }
    __syncthreads();

    const int bm = tid >> 4, cc = tid & 15;
    const int mtL = bm >> 4, rr = bm & 15;
    float mval;
    {
      const float* zb = (const float*)(smem + O_ZB);
      float zi = zb[(mtL * 4 + 0) * 256 + rr * 16 + cc];
      float zf = zb[(mtL * 4 + 1) * 256 + rr * 16 + cc];
      float zg = zb[(mtL * 4 + 2) * 256 + rr * 16 + cc];
      float zo = zb[(mtL * 4 + 3) * 256 + rr * 16 + cc];
      float* cb = (float*)(smem + O_CB);
      float cold = cb[bm * 16 + cc];
      mval = mb[bm];
      float cn = sigm(zf) * cold + sigm(zi) * tanhfast(zg);
      float hnew = sigm(zo) * tanhfast(cn);
      float cbl = mval * cn + (1.f - mval) * cold;
      cb[bm * 16 + cc] = cbl;
      float hold = bf2f(*(const uint16_t*)(smem + O_HF + fragAddr(bm, g * HC + cc)));
      float hbl = mval * hnew + (1.f - mval) * hold;
      const int tact = dir ? (SS - 1 - t) : t;
      size_t ob = ((size_t)tact * BB + bm) * (2 * HH) + (size_t)dir * HH + g * HC + cc;
      out[ob] = hbl;
      out[ob + 8388608] = cbl;
      uint32_t hb = f2bf(hnew);
      uint32_t pv = (uint32_t)__shfl_xor((int)hb, 1);
      if ((tid & 1) == 0) {
        uint32_t word = (hb & 0xffffu) | (pv << 16);
        __hip_atomic_store(&HbufP[g * 256 + (tid >> 1)], word,
                           __ATOMIC_RELAXED, __HIP_MEMORY_SCOPE_AGENT);
      }
    }
    __syncthreads();
    if (tid == 0)
      __hip_atomic_store(&flagH[g * 16], (uint32_t)(t + 1),
                         __ATOMIC_RELAXED, __HIP_MEMORY_SCOPE_AGENT);

    uint32_t oldw[2][4];
    #pragma unroll
    for (int ssl = 0; ssl < 2; ++ssl) {
      const int sl = w + ssl * 8;
      if (lane == 0) {
        while (__hip_atomic_load(&flagH[sl * 16], __ATOMIC_RELAXED,
                                 __HIP_MEMORY_SCOPE_AGENT) < (uint32_t)(t + 1)) {}
      }
      const uint32_t* src = HbufP + sl * 256;
      #pragma unroll
      for (int ww = 0; ww < 4; ++ww) {
        const int word = ww * 64 + lane;
        uint32_t v = __hip_atomic_load(&src[word], __ATOMIC_RELAXED, __HIP_MEMORY_SCOPE_AGENT);
        const int mrow = word >> 3, c0 = (word & 7) * 2;
        const int fa = fragAddr(mrow, sl * HC + c0);
        oldw[ssl][ww] = *(uint32_t*)(smem + O_HF + fa);
        *(uint32_t*)(smem + O_HF + fa) = v;
      }
    }
    __syncthreads();

    if (w == 2 || w == 3) {
      f32x4 aU = {0.f, 0.f, 0.f, 0.f};
      #pragma unroll
      for (int kk = 0; kk < 8; ++kk) {
        bf16x8 ah = *(const bf16x8*)(smem + O_HF + (((w & 1) * 8 + kk) << 10) + lane * 16);
        aU = mfma16(ah, UF[kk], aU);
      }
      float* ub = (float*)(smem + O_UH);
      #pragma unroll
      for (int i = 0; i < 4; ++i)
        ub[(w & 1) * 256 + (lq * 4 + i) * 16 + lr] = aU[i];
    }
    __syncthreads();

    #pragma unroll
    for (int ssl = 0; ssl < 2; ++ssl) {
      const int sl = w + ssl * 8;
      #pragma unroll
      for (int ww = 0; ww < 4; ++ww) {
        const int word = ww * 64 + lane;
        const int mrow = word >> 3, c0 = (word & 7) * 2;
        const int fa = fragAddr(mrow, sl * HC + c0);
        uint32_t nv = *(uint32_t*)(smem + O_HF + fa);
        uint32_t ov = oldw[ssl][ww];
        float mv = mb[mrow];
        float b0 = mv * bf2f(nv & 0xffffu) + (1.f - mv) * bf2f(ov & 0xffffu);
        float b1 = mv * bf2f(nv >> 16)     + (1.f - mv) * bf2f(ov >> 16);
        *(uint32_t*)(smem + O_HF + fa) = (f2bf(b0) & 0xffffu) | (f2bf(b1) << 16);
      }
    }
    {
      const float* ub1 = (const float*)(smem + O_US);
      const float* ub2 = (const float*)(smem + O_UH);
      float sv = ub1[mtL * 256 + rr * 16 + cc] + ub2[mtL * 256 + rr * 16 + cc] + bsreg;
      float snew = tanhfast(sv);
      float sold = bf2f(*(const uint16_t*)(smem + O_SF + fragAddr(bm, g * HC + cc)));
      float sbl = mval * snew + (1.f - mval) * sold;
      const int tact = dir ? (SS - 1 - t) : t;
      out[((size_t)tact * BB + bm) * (2 * HH) + (size_t)dir * HH + g * HC + cc + 16777216] = sbl;
      uint32_t sb = f2bf(snew);
      uint32_t pv = (uint32_t)__shfl_xor((int)sb, 1);
      if ((tid & 1) == 0) {
        uint32_t word = (sb & 0xffffu) | (pv << 16);
        __hip_atomic_store(&SbufP[g * 256 + (tid >> 1)], word,
                           __ATOMIC_RELAXED, __HIP_MEMORY_SCOPE_AGENT);
      }
    }
    __syncthreads();
    if (tid == 0)
      __hip_atomic_store(&flagS[g * 16], (uint32_t)(t + 1),
                         __ATOMIC_RELAXED, __HIP_MEMORY_SCOPE_AGENT);

    #pragma unroll
    for (int ssl = 0; ssl < 2; ++ssl) {
      const int sl = w + ssl * 8;
      if (lane == 0) {
        while (__hip_atomic_load(&flagS[sl * 16], __ATOMIC_RELAXED,
                                 __HIP_MEMORY_SCOPE_AGENT) < (uint32_t)(t + 1)) {}
      }
      const uint32_t* src = SbufP + sl * 256;
      #pragma unroll
      for (int ww = 0; ww < 4; ++ww) {
        const int word = ww * 64 + lane;
        uint32_t v = __hip_atomic_load(&src[word], __ATOMIC_RELAXED, __HIP_MEMORY_SCOPE_AGENT);
        const int mrow = word >> 3, c0 = (word & 7) * 2;
        const int fa = fragAddr(mrow, sl * HC + c0);
        uint32_t ov = *(uint32_t*)(smem + O_SF + fa);
        float mv = mb[mrow];
        float b0 = mv * bf2f(v & 0xffffu) + (1.f - mv) * bf2f(ov & 0xffffu);
        float b1 = mv * bf2f(v >> 16)     + (1.f - mv) * bf2f(ov >> 16);
        *(uint32_t*)(smem + O_SF + fa) = (f2bf(b0) & 0xffffu) | (f2bf(b1) << 16);
      }
    }
    if (t + 1 < SS) {
      const int bm2 = tid >> 4, e0 = (tid & 15) * 16;
      #pragma unroll
      for (int hfi = 0; hfi < 2; ++hfi) {
        bf16x8 vv;
        #pragma unroll
        for (int i = 0; i < 8; ++i) vv[i] = (short)f2bf(xr[hfi * 8 + i]);
        *(bf16x8*)(smem + O_XB + fragAddr(bm2, e0 + hfi * 8)) = vv;
      }
      float* mbn = (float*)(smem + O_MB + ((t + 1) & 1) * 128);
      if (tid < BB) mbn[tid] = mreg;
    }
    __syncthreads();
  }
}

extern "C" void kernel_launch(void* const* d_in, const int* in_sizes, int n_in,
                              void* d_out, int out_size, void* d_ws, size_t ws_size,
                              hipStream_t stream) {
  (void)in_sizes; (void)n_in; (void)out_size;
  const float* x    = (const float*)d_in[0];
  const float* mask = (const float*)d_in[1];
  const float* Wx_f = (const float*)d_in[3];
  const float* Wh_f = (const float*)d_in[4];
  const float* Ws_f = (const float*)d_in[5];
  const float* b_f  = (const float*)d_in[6];
  const float* Us_f = (const float*)d_in[7];
  const float* Uh_f = (const float*)d_in[8];
  const float* bs_f = (const float*)d_in[9];
  const float* Wx_r = (const float*)d_in[10];
  const float* Wh_r = (const float*)d_in[11];
  const float* Ws_r = (const float*)d_in[12];
  const float* b_r  = (const float*)d_in[13];
  const float* Us_r = (const float*)d_in[14];
  const float* Uh_r = (const float*)d_in[15];
  const float* bs_r = (const float*)d_in[16];
  float* out = (float*)d_out;
  uint32_t* ws = (uint32_t*)d_ws;

  const size_t XZ_WORDS = (size_t)2 * SS * H4 * BB / 2;  // bf16 elems / 2 = 16777216 words
  const size_t need = (XZ_WORDS + 512 + 16384) * 4;

  if (ws_size >= need) {
    unsigned short* xz = (unsigned short*)ws;
    uint32_t* flags = ws + XZ_WORDS;
    uint32_t* hbuf  = flags + 512;
    zero_words<<<dim3(1), dim3(512), 0, stream>>>(flags, 512);
    xz_prepass<<<dim3(256), dim3(512), 0, stream>>>(x, Wx_f, b_f, Wx_r, b_r, xz);
    slstm_fast<<<dim3(NWG), dim3(NTHR), 0, stream>>>(
        mask, Wh_f, Ws_f, Us_f, Uh_f, bs_f,
        Wh_r, Ws_r, Us_r, Uh_r, bs_r, xz, out, flags, hbuf);
  } else {
    init_flags<<<dim3(4), dim3(256), 0, stream>>>(ws);
    slstm_persistent<<<dim3(NWG), dim3(NTHR), 0, stream>>>(
        x, mask, Wx_f, Wh_f, Ws_f, b_f, Us_f, Uh_f, bs_f,
        Wx_r, Wh_r, Ws_r, b_r, Us_r, Uh_r, bs_r, out, ws);
  }
}

// Round 3
// 2974.614 us; speedup vs baseline: 1.8921x; 1.8921x over previous
//
#include <hip/hip_runtime.h>
#include <stdint.h>

// Problem constants
#define BB   32      // batch
#define SS   512     // seq len
#define EE   256     // input dim
#define HH   256     // hidden
#define H4   1024    // 4*H
#define HC   16
#define NG   16
#define NWG  32
#define NTHR 512

// fast2 kernel geometry
#define NGD  8       // slices (WGs) per direction
#define SW   32      // h-columns per slice

typedef short bf16x8 __attribute__((ext_vector_type(8)));
typedef float f32x4  __attribute__((ext_vector_type(4)));
typedef unsigned short u16x4 __attribute__((ext_vector_type(4)));

// ---- fallback (round-1) kernel LDS offsets ----
#define O_HF  0
#define O_SF  16384
#define O_XB  32768
#define O_ZB  49152
#define O_US  57344
#define O_UH  59392
#define O_CB  61440
#define O_MB  63488
#define O_SMEM 63744

// ---- fast2 LDS offsets ----
#define F_HF  0        // h fragments, 16KB
#define F_SF  16384    // s fragments, 16KB
#define F_ZB  32768    // z tiles f32 [8][16][33] = 16896 B
#define F_US  49664    // s@Us f32 [32][33] = 4224 B
#define F_UH  53888    // hnew@Uh f32 [32][33] = 4224 B
#define F_CB  58112    // c state f32 [32][33] = 4224 B
#define F_MB  62336    // mask [2][32] f32 (256B) + allones int[2]
#define F_SMEM 62608

__device__ __forceinline__ float bf2f(uint32_t u) {
  union { uint32_t i; float f; } v; v.i = u << 16; return v.f;
}
__device__ __forceinline__ uint32_t f2bf(float f) {
  union { float f; uint32_t i; } v; v.f = f;
  return (v.i + 0x7fffu + ((v.i >> 16) & 1u)) >> 16;
}
__device__ __forceinline__ float sigm(float x) { return 1.f / (1.f + __expf(-x)); }
__device__ __forceinline__ float tanhfast(float x) {
  float e = __expf(2.f * x);
  return 1.f - 2.f / (1.f + e);
}
__device__ __forceinline__ int fragAddr(int m, int k) {
  return (((m >> 4) * 8 + (k >> 5)) << 10) + (((m & 15) + (((k >> 3) & 3) << 4)) << 4) + ((k & 7) << 1);
}
__device__ __forceinline__ f32x4 mfma16(bf16x8 a, bf16x8 b, f32x4 c) {
  return __builtin_amdgcn_mfma_f32_16x16x32_bf16(a, b, c, 0, 0, 0);
}
__device__ __forceinline__ uint32_t blend2(uint32_t nw, uint32_t ow, float mv) {
  float n0 = bf2f(nw & 0xffffu), n1 = bf2f(nw >> 16);
  float o0 = bf2f(ow & 0xffffu), o1 = bf2f(ow >> 16);
  float b0 = mv * n0 + (1.f - mv) * o0;
  float b1 = mv * n1 + (1.f - mv) * o1;
  return (f2bf(b0) & 0xffffu) | (f2bf(b1) << 16);
}

// consume one 2KB slice ([32 m][32 k] bf16) into fragment region dstBase.
__device__ __forceinline__ void consume_slice(const unsigned long long* __restrict__ src,
                                              char* dstBase, int sl, int lane,
                                              bool doBlend, bool doStash,
                                              const float* mbv, uint4* stash) {
  #pragma unroll
  for (int j = 0; j < 2; ++j) {
    const int u = lane + 64 * j;
    const int m = u & 31;
    const int b = u >> 5;                  // 0..3
    const unsigned long long* s8 = src + (m * 8 + b * 2);
    unsigned long long lo = __hip_atomic_load(s8,     __ATOMIC_RELAXED, __HIP_MEMORY_SCOPE_AGENT);
    unsigned long long hi = __hip_atomic_load(s8 + 1, __ATOMIC_RELAXED, __HIP_MEMORY_SCOPE_AGENT);
    char* dst = dstBase + (((m >> 4) * 8 + sl) << 10) + (((m & 15) + 16 * b) << 4);
    uint4 nv;
    nv.x = (uint32_t)lo; nv.y = (uint32_t)(lo >> 32);
    nv.z = (uint32_t)hi; nv.w = (uint32_t)(hi >> 32);
    if (doBlend | doStash) {
      uint4 ov = *(const uint4*)dst;
      if (doStash) stash[j] = ov;
      if (doBlend) {
        float mv = mbv[m];
        nv.x = blend2(nv.x, ov.x, mv); nv.y = blend2(nv.y, ov.y, mv);
        nv.z = blend2(nv.z, ov.z, mv); nv.w = blend2(nv.w, ov.w, mv);
      }
    }
    *(uint4*)dst = nv;
  }
}

__device__ __forceinline__ void reblend_slice(char* dstBase, int sl, int lane,
                                              const float* mbv, const uint4* stash) {
  #pragma unroll
  for (int j = 0; j < 2; ++j) {
    const int u = lane + 64 * j;
    const int m = u & 31;
    const int b = u >> 5;
    char* dst = dstBase + (((m >> 4) * 8 + sl) << 10) + (((m & 15) + 16 * b) << 4);
    uint4 nv = *(const uint4*)dst;
    uint4 ov = stash[j];
    float mv = mbv[m];
    nv.x = blend2(nv.x, ov.x, mv); nv.y = blend2(nv.y, ov.y, mv);
    nv.z = blend2(nv.z, ov.z, mv); nv.w = blend2(nv.w, ov.w, mv);
    *(uint4*)dst = nv;
  }
}

// publish this thread's (m, cc) and (m, cc+16) values into row buffer (8B UC stores)
__device__ __forceinline__ void publish_pair(unsigned long long* dstRow, int cc,
                                             float v0, float v1) {
  uint32_t h0 = f2bf(v0);
  uint32_t p0 = (uint32_t)__shfl_xor((int)h0, 1);
  uint32_t w0 = (h0 & 0xffffu) | (p0 << 16);          // valid on even cc
  uint32_t w0b = (uint32_t)__shfl_xor((int)w0, 2);    // from cc+2
  uint32_t h1 = f2bf(v1);
  uint32_t p1 = (uint32_t)__shfl_xor((int)h1, 1);
  uint32_t w1 = (h1 & 0xffffu) | (p1 << 16);
  uint32_t w1b = (uint32_t)__shfl_xor((int)w1, 2);
  if ((cc & 3) == 0) {
    unsigned long long q0 = ((unsigned long long)w0b << 32) | (unsigned long long)w0;
    unsigned long long q1 = ((unsigned long long)w1b << 32) | (unsigned long long)w1;
    __hip_atomic_store(dstRow + (cc >> 2),     q0, __ATOMIC_RELAXED, __HIP_MEMORY_SCOPE_AGENT);
    __hip_atomic_store(dstRow + 4 + (cc >> 2), q1, __ATOMIC_RELAXED, __HIP_MEMORY_SCOPE_AGENT);
  }
}

__global__ void init_flags(uint32_t* f) {
  int i = blockIdx.x * blockDim.x + threadIdx.x;
  if (i < 1024) f[i] = 0u;
}
__global__ void zero_words(uint32_t* p, int n) {
  int i = blockIdx.x * blockDim.x + threadIdx.x;
  if (i < n) p[i] = 0u;
}

// ============================================================================
// Pre-pass: XZ[dir][t][col][b] = (x[b,t,:] @ Wx + b)[col]  (bf16)  [proven r2]
// ============================================================================
__global__ void __launch_bounds__(512)
xz_prepass(const float* __restrict__ x,
           const float* __restrict__ Wx_f, const float* __restrict__ b_f,
           const float* __restrict__ Wx_r, const float* __restrict__ b_r,
           unsigned short* __restrict__ xz) {
  __shared__ __align__(16) char smem[65536];
  const int bid = blockIdx.x;
  const int dir = bid >> 7;
  const int t0  = (bid & 127) * 4;
  const int tid = threadIdx.x;
  const int w = tid >> 6, lane = tid & 63;
  const int lr = lane & 15, lq = lane >> 4;
  const float* W  = dir ? Wx_r : Wx_f;
  const float* bv = dir ? b_r  : b_f;

  {
    const int bm = tid >> 4, e0 = (tid & 15) * 16;
    for (int tt = 0; tt < 4; ++tt) {
      const float* xs = x + ((size_t)bm * SS + (t0 + tt)) * EE + e0;
      float xr[16];
      #pragma unroll
      for (int i = 0; i < 16; ++i) xr[i] = xs[i];
      #pragma unroll
      for (int hfi = 0; hfi < 2; ++hfi) {
        bf16x8 vv;
        #pragma unroll
        for (int i = 0; i < 8; ++i) vv[i] = (short)f2bf(xr[hfi * 8 + i]);
        *(bf16x8*)(smem + tt * 16384 + fragAddr(bm, e0 + hfi * 8)) = vv;
      }
    }
  }
  __syncthreads();

  for (int j = 0; j < 8; ++j) {
    const int col = (w * 8 + j) * 16 + lr;
    const float breg = bv[col];
    f32x4 acc[4][2];
    #pragma unroll
    for (int tt = 0; tt < 4; ++tt)
      #pragma unroll
      for (int m = 0; m < 2; ++m) {
        acc[tt][m][0] = breg; acc[tt][m][1] = breg;
        acc[tt][m][2] = breg; acc[tt][m][3] = breg;
      }
    #pragma unroll
    for (int kk = 0; kk < 8; ++kk) {
      bf16x8 bfr;
      #pragma unroll
      for (int i = 0; i < 8; ++i)
        bfr[i] = (short)f2bf(W[(size_t)(kk * 32 + lq * 8 + i) * H4 + col]);
      #pragma unroll
      for (int tt = 0; tt < 4; ++tt) {
        bf16x8 a0 = *(const bf16x8*)(smem + tt * 16384 + (kk << 10) + lane * 16);
        bf16x8 a1 = *(const bf16x8*)(smem + tt * 16384 + ((8 + kk) << 10) + lane * 16);
        acc[tt][0] = mfma16(a0, bfr, acc[tt][0]);
        acc[tt][1] = mfma16(a1, bfr, acc[tt][1]);
      }
    }
    #pragma unroll
    for (int tt = 0; tt < 4; ++tt)
      #pragma unroll
      for (int m = 0; m < 2; ++m) {
        u16x4 pk;
        #pragma unroll
        for (int i = 0; i < 4; ++i) pk[i] = (unsigned short)f2bf(acc[tt][m][i]);
        *(u16x4*)(xz + (((size_t)dir * SS + (t0 + tt)) * H4 + col) * BB + m * 16 + lq * 4) = pk;
      }
  }
}

// ============================================================================
// fast2 persistent kernel: 8 WGs/dir, 2 overlapped exchanges, mask fast path.
// ============================================================================
__global__ void __launch_bounds__(NTHR)
slstm_fast2(const float* __restrict__ mask,
            const float* Wh_f, const float* Ws_f,
            const float* Us_f, const float* Uh_f, const float* bs_f,
            const float* Wh_r, const float* Ws_r,
            const float* Us_r, const float* Uh_r, const float* bs_r,
            const unsigned short* __restrict__ xz,
            float* __restrict__ out,
            uint32_t* __restrict__ flags,
            unsigned long long* __restrict__ bufs) {
  __shared__ __align__(16) char smem[F_SMEM];

  const int bid = blockIdx.x;    // 0..15
  const int dir = bid >> 3;
  const int sid = bid & 7;
  const int tid = threadIdx.x;
  const int w = tid >> 6;
  const int lane = tid & 63;
  const int lr = lane & 15, lq = lane >> 4;
  const int mt = w & 1, q = w >> 1;

  const float* Wh = dir ? Wh_r : Wh_f;
  const float* Ws = dir ? Ws_r : Ws_f;
  const float* Us = dir ? Us_r : Us_f;
  const float* Uh = dir ? Uh_r : Uh_f;
  const float* bs = dir ? bs_r : bs_f;

  uint32_t* flagH = flags + dir * (NGD * 16);
  uint32_t* flagS = flags + 256 + dir * (NGD * 16);
  unsigned long long* hbuf = bufs + (size_t)dir * 4096;          // [2par][8sl][256 ull]
  unsigned long long* sbuf = bufs + 8192 + (size_t)dir * 4096;

  // ---- persistent weight fragments ----
  bf16x8 WhF[2][8], WsF[2][8], UF[8];
  #pragma unroll
  for (int nt = 0; nt < 2; ++nt) {
    const int col = q * HH + sid * SW + nt * 16 + lr;
    #pragma unroll
    for (int kk = 0; kk < 8; ++kk) {
      bf16x8 vh, vs;
      #pragma unroll
      for (int i = 0; i < 8; ++i) {
        const int k = kk * 32 + lq * 8 + i;
        vh[i] = (short)f2bf(Wh[(size_t)k * H4 + col]);
        vs[i] = (short)f2bf(Ws[(size_t)k * H4 + col]);
      }
      WhF[nt][kk] = vh; WsF[nt][kk] = vs;
    }
  }
  const int mtU = (w & 3) >> 1, ntU = w & 1;
  {
    const float* U = (w < 4) ? Us : Uh;
    const int colU = sid * SW + ntU * 16 + lr;
    #pragma unroll
    for (int kk = 0; kk < 8; ++kk) {
      bf16x8 vu;
      #pragma unroll
      for (int i = 0; i < 8; ++i) {
        const int k = kk * 32 + lq * 8 + i;
        vu[i] = (short)f2bf(U[(size_t)k * HH + colU]);
      }
      UF[kk] = vu;
    }
  }
  const float bs0 = bs[sid * SW + (tid & 15)];
  const float bs1 = bs[sid * SW + (tid & 15) + 16];

  // ---- zero state ----
  {
    uint4* p = (uint4*)smem;     // HF+SF = 32KB
    for (int i = tid; i < 2048; i += NTHR) p[i] = make_uint4(0u, 0u, 0u, 0u);
    float* cb = (float*)(smem + F_CB);
    for (int i = tid; i < 32 * 33; i += NTHR) cb[i] = 0.f;
  }
  // ---- mask_0 / allones_0 / xz_0 ----
  const int ta0 = dir ? (SS - 1) : 0;
  {
    float mr = 0.f;
    if (tid < 32) mr = mask[(size_t)tid * SS + ta0];
    if (w == 0) {
      if (tid < 32) ((float*)(smem + F_MB))[tid] = mr;
      bool p = (lane < 32) ? (mr == 1.f) : true;
      unsigned long long bal = __ballot(p);
      if (lane == 0) ((int*)(smem + F_MB + 256))[0] = (bal == ~0ull) ? 1 : 0;
    }
  }
  const int zc0 = q * HH + sid * SW + lr;
  f32x4 accZ0, accZ1;
  {
    u16x4 xa = *(const u16x4*)(xz + (((size_t)dir * SS + ta0) * H4 + zc0) * BB + mt * 16 + lq * 4);
    u16x4 xb = *(const u16x4*)(xz + (((size_t)dir * SS + ta0) * H4 + zc0 + 16) * BB + mt * 16 + lq * 4);
    #pragma unroll
    for (int i = 0; i < 4; ++i) { accZ0[i] = bf2f(xa[i]); accZ1[i] = bf2f(xb[i]); }
  }
  __syncthreads();

  for (int t = 0; t < SS; ++t) {
    const int par = t & 1;
    const float* mb  = (const float*)(smem + F_MB + par * 128);
    const float* mbp = (const float*)(smem + F_MB + (par ^ 1) * 128);
    const bool ao  = ((const int*)(smem + F_MB + 256))[par] != 0;
    const bool aop = ((const int*)(smem + F_MB + 256))[par ^ 1] != 0;

    // ---- A: consume s_t (published by peers at end of step t-1) ----
    if (t > 0) {
      if (lane == 0) {
        while (__hip_atomic_load(&flagS[w * 16], __ATOMIC_RELAXED,
                                 __HIP_MEMORY_SCOPE_AGENT) < (uint32_t)t) {}
      }
      const unsigned long long* src = sbuf + ((size_t)par * NGD + w) * 256;
      uint4 dummy[2];
      consume_slice(src, smem + F_SF, w, lane, !aop, false, mbp, dummy);
    }
    __syncthreads();   // bar1

    // ---- B: accZ += s_t @ Ws ; spill z ----
    #pragma unroll
    for (int kk = 0; kk < 8; ++kk) {
      bf16x8 as = *(const bf16x8*)(smem + F_SF + ((mt * 8 + kk) << 10) + lane * 16);
      accZ0 = mfma16(as, WsF[0][kk], accZ0);
      accZ1 = mfma16(as, WsF[1][kk], accZ1);
    }
    {
      float* zb = (float*)(smem + F_ZB);
      const int base = (mt * 4 + q) * 528;
      #pragma unroll
      for (int i = 0; i < 4; ++i) {
        zb[base + (lq * 4 + i) * 33 + lr]      = accZ0[i];
        zb[base + (lq * 4 + i) * 33 + 16 + lr] = accZ1[i];
      }
    }
    __syncthreads();   // bar2

    // ---- C: gates + publish h_new ----
    const int m = tid >> 4, cc = tid & 15;
    const int mtL = m >> 4, rr = m & 15;
    const float mval = mb[m];
    float hnew0, hnew1, hbl0, hbl1, cbl0, cbl1;
    {
      const float* zb = (const float*)(smem + F_ZB);
      float* cb = (float*)(smem + F_CB);
      #pragma unroll
      for (int half = 0; half < 2; ++half) {
        const int n = cc + half * 16;
        const float zi = zb[(mtL * 4 + 0) * 528 + rr * 33 + n];
        const float zf = zb[(mtL * 4 + 1) * 528 + rr * 33 + n];
        const float zg = zb[(mtL * 4 + 2) * 528 + rr * 33 + n];
        const float zo = zb[(mtL * 4 + 3) * 528 + rr * 33 + n];
        const float cold = cb[m * 33 + n];
        const float cn = sigm(zf) * cold + sigm(zi) * tanhfast(zg);
        const float hn = sigm(zo) * tanhfast(cn);
        float cblv, hblv;
        if (ao) { cblv = cn; hblv = hn; }
        else {
          cblv = mval * cn + (1.f - mval) * cold;
          const float hold = bf2f(*(const uint16_t*)(smem + F_HF + fragAddr(m, sid * SW + n)));
          hblv = mval * hn + (1.f - mval) * hold;
        }
        cb[m * 33 + n] = cblv;
        if (half == 0) { hnew0 = hn; hbl0 = hblv; cbl0 = cblv; }
        else           { hnew1 = hn; hbl1 = hblv; cbl1 = cblv; }
      }
      publish_pair(hbuf + ((size_t)par * NGD + sid) * 256 + m * 8, cc, hnew0, hnew1);
    }
    __syncthreads();   // bar3
    if (tid == 0)
      __hip_atomic_store(&flagH[sid * 16], (uint32_t)(t + 1),
                         __ATOMIC_RELAXED, __HIP_MEMORY_SCOPE_AGENT);

    // ---- D (overlap h-RTT): outputs, prefetch, Us GEMM ----
    const int tact = dir ? (SS - 1 - t) : t;
    {
      const size_t ob = ((size_t)tact * BB + m) * (2 * HH) + (size_t)dir * HH + sid * SW + cc;
      __builtin_nontemporal_store(hbl0, &out[ob]);
      __builtin_nontemporal_store(hbl1, &out[ob + 16]);
      __builtin_nontemporal_store(cbl0, &out[ob + 8388608]);
      __builtin_nontemporal_store(cbl1, &out[ob + 16 + 8388608]);
    }
    u16x4 nxa = {0, 0, 0, 0}, nxb = {0, 0, 0, 0};
    if (t + 1 < SS) {
      const int ta = dir ? (SS - 2 - t) : (t + 1);
      nxa = *(const u16x4*)(xz + (((size_t)dir * SS + ta) * H4 + zc0) * BB + mt * 16 + lq * 4);
      nxb = *(const u16x4*)(xz + (((size_t)dir * SS + ta) * H4 + zc0 + 16) * BB + mt * 16 + lq * 4);
      float mr = 0.f;
      if (tid < 32) mr = mask[(size_t)tid * SS + ta];
      if (w == 0) {
        if (tid < 32) ((float*)(smem + F_MB + (par ^ 1) * 128))[tid] = mr;
        bool p = (lane < 32) ? (mr == 1.f) : true;
        unsigned long long bal = __ballot(p);
        if (lane == 0) ((int*)(smem + F_MB + 256))[par ^ 1] = (bal == ~0ull) ? 1 : 0;
      }
    }
    if (w < 4) {   // Us GEMM on s_t
      f32x4 accU = {0.f, 0.f, 0.f, 0.f};
      #pragma unroll
      for (int kk = 0; kk < 8; ++kk) {
        bf16x8 as = *(const bf16x8*)(smem + F_SF + ((mtU * 8 + kk) << 10) + lane * 16);
        accU = mfma16(as, UF[kk], accU);
      }
      float* us = (float*)(smem + F_US);
      #pragma unroll
      for (int i = 0; i < 4; ++i)
        us[(mtU * 16 + lq * 4 + i) * 33 + ntU * 16 + lr] = accU[i];
    }

    // ---- E: poll + consume h_new (raw; stash old if blending needed) ----
    uint4 stOld[2];
    {
      if (lane == 0) {
        while (__hip_atomic_load(&flagH[w * 16], __ATOMIC_RELAXED,
                                 __HIP_MEMORY_SCOPE_AGENT) < (uint32_t)(t + 1)) {}
      }
      const unsigned long long* src = hbuf + ((size_t)par * NGD + w) * 256;
      consume_slice(src, smem + F_HF, w, lane, false, !ao, mb, stOld);
    }
    __syncthreads();   // bar4

    // ---- F: Uh GEMM (waves 4..7) on pre-blend h_new ----
    if (w >= 4) {
      f32x4 accU = {0.f, 0.f, 0.f, 0.f};
      #pragma unroll
      for (int kk = 0; kk < 8; ++kk) {
        bf16x8 ah = *(const bf16x8*)(smem + F_HF + ((mtU * 8 + kk) << 10) + lane * 16);
        accU = mfma16(ah, UF[kk], accU);
      }
      float* uh = (float*)(smem + F_UH);
      #pragma unroll
      for (int i = 0; i < 4; ++i)
        uh[(mtU * 16 + lq * 4 + i) * 33 + ntU * 16 + lr] = accU[i];
    }
    __syncthreads();   // bar5
    if (!ao) {         // generic mask path: blend HF to h_{t+1}
      reblend_slice(smem + F_HF, w, lane, mb, stOld);
      __syncthreads();
    }

    // ---- G: s tail ----
    {
      const float* us = (const float*)(smem + F_US);
      const float* uh = (const float*)(smem + F_UH);
      const float sv0 = us[m * 33 + cc]      + uh[m * 33 + cc]      + bs0;
      const float sv1 = us[m * 33 + cc + 16] + uh[m * 33 + cc + 16] + bs1;
      const float sn0 = tanhfast(sv0);
      const float sn1 = tanhfast(sv1);
      float sbl0v, sbl1v;
      if (ao) { sbl0v = sn0; sbl1v = sn1; }
      else {
        const float so0 = bf2f(*(const uint16_t*)(smem + F_SF + fragAddr(m, sid * SW + cc)));
        const float so1 = bf2f(*(const uint16_t*)(smem + F_SF + fragAddr(m, sid * SW + cc + 16)));
        sbl0v = mval * sn0 + (1.f - mval) * so0;
        sbl1v = mval * sn1 + (1.f - mval) * so1;
      }
      const size_t obS = ((size_t)tact * BB + m) * (2 * HH) + (size_t)dir * HH + sid * SW + cc + 16777216;
      __builtin_nontemporal_store(sbl0v, &out[obS]);
      __builtin_nontemporal_store(sbl1v, &out[obS + 16]);
      if (t + 1 < SS)
        publish_pair(sbuf + ((size_t)(par ^ 1) * NGD + sid) * 256 + m * 8, cc, sn0, sn1);
    }
    __syncthreads();   // bar6
    if (tid == 0 && t + 1 < SS)
      __hip_atomic_store(&flagS[sid * 16], (uint32_t)(t + 1),
                         __ATOMIC_RELAXED, __HIP_MEMORY_SCOPE_AGENT);

    // ---- H (overlap s-RTT): next-step accZ = xz_{t+1} + h_{t+1} @ Wh ----
    if (t + 1 < SS) {
      #pragma unroll
      for (int i = 0; i < 4; ++i) { accZ0[i] = bf2f(nxa[i]); accZ1[i] = bf2f(nxb[i]); }
      #pragma unroll
      for (int kk = 0; kk < 8; ++kk) {
        bf16x8 ah = *(const bf16x8*)(smem + F_HF + ((mt * 8 + kk) << 10) + lane * 16);
        accZ0 = mfma16(ah, WhF[0][kk], accZ0);
        accZ1 = mfma16(ah, WhF[1][kk], accZ1);
      }
    }
  }
}

// ============================================================================
// Fallback: proven round-1 kernel (used only if ws too small).
// ============================================================================
__global__ void __launch_bounds__(NTHR)
slstm_persistent(const float* __restrict__ x, const float* __restrict__ mask,
                 const float* Wx_f, const float* Wh_f, const float* Ws_f, const float* b_f,
                 const float* Us_f, const float* Uh_f, const float* bs_f,
                 const float* Wx_r, const float* Wh_r, const float* Ws_r, const float* b_r,
                 const float* Us_r, const float* Uh_r, const float* bs_r,
                 float* __restrict__ out, uint32_t* __restrict__ wsbase) {
  __shared__ __align__(16) char smem[O_SMEM];

  const int bid = blockIdx.x;
  const int dir = bid >> 4;
  const int g   = bid & 15;
  const int tid = threadIdx.x;
  const int w    = tid >> 6;
  const int lane = tid & 63;
  const int lr = lane & 15, lq = lane >> 4;
  const int mt = w & 1;
  const int q  = w >> 1;

  const float* Wx = dir ? Wx_r : Wx_f;
  const float* Wh = dir ? Wh_r : Wh_f;
  const float* Ws = dir ? Ws_r : Ws_f;
  const float* bv = dir ? b_r  : b_f;
  const float* Us = dir ? Us_r : Us_f;
  const float* Uh = dir ? Uh_r : Uh_f;
  const float* bs = dir ? bs_r : bs_f;

  uint32_t* flags = wsbase;
  uint32_t* hbufB = wsbase + 1024;
  uint32_t* sbufB = wsbase + 1024 + 16384;
  uint32_t* flagH = flags + (dir * 2 + 0) * NG * 16;
  uint32_t* flagS = flags + (dir * 2 + 1) * NG * 16;

  bf16x8 WxF[8], WhF[8], WsF[8], UF[8];
  {
    const int col = q * HH + g * HC + lr;
    #pragma unroll
    for (int kk = 0; kk < 8; ++kk) {
      bf16x8 vx, vh, vs;
      #pragma unroll
      for (int i = 0; i < 8; ++i) {
        int k = kk * 32 + lq * 8 + i;
        vx[i] = (short)f2bf(Wx[k * H4 + col]);
        vh[i] = (short)f2bf(Wh[k * H4 + col]);
        vs[i] = (short)f2bf(Ws[k * H4 + col]);
      }
      WxF[kk] = vx; WhF[kk] = vh; WsF[kk] = vs;
    }
  }
  if (w < 4) {
    const float* U = (w < 2) ? Us : Uh;
    const int colU = g * HC + lr;
    #pragma unroll
    for (int kk = 0; kk < 8; ++kk) {
      bf16x8 vu;
      #pragma unroll
      for (int i = 0; i < 8; ++i) {
        int k = kk * 32 + lq * 8 + i;
        vu[i] = (short)f2bf(U[k * HH + colU]);
      }
      UF[kk] = vu;
    }
  }
  const float breg  = bv[q * HH + g * HC + lr];
  const float bsreg = bs[g * HC + (tid & 15)];

  {
    uint4* p = (uint4*)(smem);
    for (int i = tid; i < 2048; i += NTHR) p[i] = make_uint4(0u, 0u, 0u, 0u);
    float* cb = (float*)(smem + O_CB);
    for (int i = tid; i < BB * HC; i += NTHR) cb[i] = 0.f;
  }
  {
    const int ta = dir ? (SS - 1) : 0;
    const int bm = tid >> 4, e0 = (tid & 15) * 16;
    const float* xs = x + ((size_t)bm * SS + ta) * EE + e0;
    float xr0[16];
    #pragma unroll
    for (int i = 0; i < 16; ++i) xr0[i] = xs[i];
    #pragma unroll
    for (int hfi = 0; hfi < 2; ++hfi) {
      bf16x8 vv;
      #pragma unroll
      for (int i = 0; i < 8; ++i) vv[i] = (short)f2bf(xr0[hfi * 8 + i]);
      *(bf16x8*)(smem + O_XB + fragAddr(bm, e0 + hfi * 8)) = vv;
    }
    if (tid < BB) ((float*)(smem + O_MB))[tid] = mask[(size_t)tid * SS + ta];
  }
  __syncthreads();

  for (int t = 0; t < SS; ++t) {
    const int par = t & 1;
    uint32_t* HbufP = hbufB + (dir * 2 + par) * (NG * 256);
    uint32_t* SbufP = sbufB + (dir * 2 + par) * (NG * 256);
    const float* mb = (const float*)(smem + O_MB + par * 128);

    f32x4 accZ; accZ[0] = breg; accZ[1] = breg; accZ[2] = breg; accZ[3] = breg;
    f32x4 accU = {0.f, 0.f, 0.f, 0.f};
    #pragma unroll
    for (int kk = 0; kk < 8; ++kk) {
      const int fb = ((mt * 8 + kk) << 10) + lane * 16;
      bf16x8 ah = *(const bf16x8*)(smem + O_HF + fb);
      bf16x8 as = *(const bf16x8*)(smem + O_SF + fb);
      bf16x8 ax = *(const bf16x8*)(smem + O_XB + fb);
      accZ = mfma16(ax, WxF[kk], accZ);
      accZ = mfma16(ah, WhF[kk], accZ);
      accZ = mfma16(as, WsF[kk], accZ);
      if (w < 2) accU = mfma16(as, UF[kk], accU);
    }

    float xr[16]; float mreg = 0.f;
    if (t + 1 < SS) {
      const int ta = dir ? (SS - 2 - t) : (t + 1);
      const int bm = tid >> 4, e0 = (tid & 15) * 16;
      const float* xs = x + ((size_t)bm * SS + ta) * EE + e0;
      #pragma unroll
      for (int i = 0; i < 16; ++i) xr[i] = xs[i];
      if (tid < BB) mreg = mask[(size_t)tid * SS + ta];
    }

    {
      float* zb = (float*)(smem + O_ZB);
      #pragma unroll
      for (int i = 0; i < 4; ++i)
        zb[(mt * 4 + q) * 256 + (lq * 4 + i) * 16 + lr] = accZ[i];
      if (w < 2) {
        float* ub = (float*)(smem + O_US);
        #pragma unroll
        for (int i = 0; i < 4; ++i)
          ub[mt * 256 + (lq * 4 + i) * 16 + lr] = accU[i];
      }
    }
    __syncthreads();

    const int bm = tid >> 4, cc = tid & 15;
    const int mtL = bm >> 4, rr = bm & 15;
    float mval;
    {
      const float* zb = (const float*)(smem + O_ZB);
      float zi = zb[(mtL * 4 + 0) * 256 + rr * 16 + cc];
      float zf = zb[(mtL * 4 + 1) * 256 + rr * 16 + cc];
      float zg = zb[(mtL * 4 + 2) * 256 + rr * 16 + cc];
      float zo = zb[(mtL * 4 + 3) * 256 + rr * 16 + cc];
      float* cb = (float*)(smem + O_CB);
      float cold = cb[bm * 16 + cc];
      mval = mb[bm];
      float cn = sigm(zf) * cold + sigm(zi) * tanhfast(zg);
      float hnew = sigm(zo) * tanhfast(cn);
      float cbl = mval * cn + (1.f - mval) * cold;
      cb[bm * 16 + cc] = cbl;
      float hold = bf2f(*(const uint16_t*)(smem + O_HF + fragAddr(bm, g * HC + cc)));
      float hbl = mval * hnew + (1.f - mval) * hold;
      const int tact = dir ? (SS - 1 - t) : t;
      size_t ob = ((size_t)tact * BB + bm) * (2 * HH) + (size_t)dir * HH + g * HC + cc;
      out[ob] = hbl;
      out[ob + 8388608] = cbl;
      uint32_t hb = f2bf(hnew);
      uint32_t pv = (uint32_t)__shfl_xor((int)hb, 1);
      if ((tid & 1) == 0) {
        uint32_t word = (hb & 0xffffu) | (pv << 16);
        __hip_atomic_store(&HbufP[g * 256 + (tid >> 1)], word,
                           __ATOMIC_RELAXED, __HIP_MEMORY_SCOPE_AGENT);
      }
    }
    __syncthreads();
    if (tid == 0)
      __hip_atomic_store(&flagH[g * 16], (uint32_t)(t + 1),
                         __ATOMIC_RELAXED, __HIP_MEMORY_SCOPE_AGENT);

    uint32_t oldw[2][4];
    #pragma unroll
    for (int ssl = 0; ssl < 2; ++ssl) {
      const int sl = w + ssl * 8;
      if (lane == 0) {
        while (__hip_atomic_load(&flagH[sl * 16], __ATOMIC_RELAXED,
                                 __HIP_MEMORY_SCOPE_AGENT) < (uint32_t)(t + 1)) {}
      }
      const uint32_t* src = HbufP + sl * 256;
      #pragma unroll
      for (int ww = 0; ww < 4; ++ww) {
        const int word = ww * 64 + lane;
        uint32_t v = __hip_atomic_load(&src[word], __ATOMIC_RELAXED, __HIP_MEMORY_SCOPE_AGENT);
        const int mrow = word >> 3, c0 = (word & 7) * 2;
        const int fa = fragAddr(mrow, sl * HC + c0);
        oldw[ssl][ww] = *(uint32_t*)(smem + O_HF + fa);
        *(uint32_t*)(smem + O_HF + fa) = v;
      }
    }
    __syncthreads();

    if (w == 2 || w == 3) {
      f32x4 aU = {0.f, 0.f, 0.f, 0.f};
      #pragma unroll
      for (int kk = 0; kk < 8; ++kk) {
        bf16x8 ah = *(const bf16x8*)(smem + O_HF + (((w & 1) * 8 + kk) << 10) + lane * 16);
        aU = mfma16(ah, UF[kk], aU);
      }
      float* ub = (float*)(smem + O_UH);
      #pragma unroll
      for (int i = 0; i < 4; ++i)
        ub[(w & 1) * 256 + (lq * 4 + i) * 16 + lr] = aU[i];
    }
    __syncthreads();

    #pragma unroll
    for (int ssl = 0; ssl < 2; ++ssl) {
      const int sl = w + ssl * 8;
      #pragma unroll
      for (int ww = 0; ww < 4; ++ww) {
        const int word = ww * 64 + lane;
        const int mrow = word >> 3, c0 = (word & 7) * 2;
        const int fa = fragAddr(mrow, sl * HC + c0);
        uint32_t nv = *(uint32_t*)(smem + O_HF + fa);
        uint32_t ov = oldw[ssl][ww];
        float mv = mb[mrow];
        float b0 = mv * bf2f(nv & 0xffffu) + (1.f - mv) * bf2f(ov & 0xffffu);
        float b1 = mv * bf2f(nv >> 16)     + (1.f - mv) * bf2f(ov >> 16);
        *(uint32_t*)(smem + O_HF + fa) = (f2bf(b0) & 0xffffu) | (f2bf(b1) << 16);
      }
    }
    {
      const float* ub1 = (const float*)(smem + O_US);
      const float* ub2 = (const float*)(smem + O_UH);
      float sv = ub1[mtL * 256 + rr * 16 + cc] + ub2[mtL * 256 + rr * 16 + cc] + bsreg;
      float snew = tanhfast(sv);
      float sold = bf2f(*(const uint16_t*)(smem + O_SF + fragAddr(bm, g * HC + cc)));
      float sbl = mval * snew + (1.f - mval) * sold;
      const int tact = dir ? (SS - 1 - t) : t;
      out[((size_t)tact * BB + bm) * (2 * HH) + (size_t)dir * HH + g * HC + cc + 16777216] = sbl;
      uint32_t sb = f2bf(snew);
      uint32_t pv = (uint32_t)__shfl_xor((int)sb, 1);
      if ((tid & 1) == 0) {
        uint32_t word = (sb & 0xffffu) | (pv << 16);
        __hip_atomic_store(&SbufP[g * 256 + (tid >> 1)], word,
                           __ATOMIC_RELAXED, __HIP_MEMORY_SCOPE_AGENT);
      }
    }
    __syncthreads();
    if (tid == 0)
      __hip_atomic_store(&flagS[g * 16], (uint32_t)(t + 1),
                         __ATOMIC_RELAXED, __HIP_MEMORY_SCOPE_AGENT);

    #pragma unroll
    for (int ssl = 0; ssl < 2; ++ssl) {
      const int sl = w + ssl * 8;
      if (lane == 0) {
        while (__hip_atomic_load(&flagS[sl * 16], __ATOMIC_RELAXED,
                                 __HIP_MEMORY_SCOPE_AGENT) < (uint32_t)(t + 1)) {}
      }
      const uint32_t* src = SbufP + sl * 256;
      #pragma unroll
      for (int ww = 0; ww < 4; ++ww) {
        const int word = ww * 64 + lane;
        uint32_t v = __hip_atomic_load(&src[word], __ATOMIC_RELAXED, __HIP_MEMORY_SCOPE_AGENT);
        const int mrow = word >> 3, c0 = (word & 7) * 2;
        const int fa = fragAddr(mrow, sl * HC + c0);
        uint32_t ov = *(uint32_t*)(smem + O_SF + fa);
        float mv = mb[mrow];
        float b0 = mv * bf2f(v & 0xffffu) + (1.f - mv) * bf2f(ov & 0xffffu);
        float b1 = mv * bf2f(v >> 16)     + (1.f - mv) * bf2f(ov >> 16);
        *(uint32_t*)(smem + O_SF + fa) = (f2bf(b0) & 0xffffu) | (f2bf(b1) << 16);
      }
    }
    if (t + 1 < SS) {
      const int bm2 = tid >> 4, e0 = (tid & 15) * 16;
      #pragma unroll
      for (int hfi = 0; hfi < 2; ++hfi) {
        bf16x8 vv;
        #pragma unroll
        for (int i = 0; i < 8; ++i) vv[i] = (short)f2bf(xr[hfi * 8 + i]);
        *(bf16x8*)(smem + O_XB + fragAddr(bm2, e0 + hfi * 8)) = vv;
      }
      float* mbn = (float*)(smem + O_MB + ((t + 1) & 1) * 128);
      if (tid < BB) mbn[tid] = mreg;
    }
    __syncthreads();
  }
}

extern "C" void kernel_launch(void* const* d_in, const int* in_sizes, int n_in,
                              void* d_out, int out_size, void* d_ws, size_t ws_size,
                              hipStream_t stream) {
  (void)in_sizes; (void)n_in; (void)out_size;
  const float* x    = (const float*)d_in[0];
  const float* mask = (const float*)d_in[1];
  const float* Wx_f = (const float*)d_in[3];
  const float* Wh_f = (const float*)d_in[4];
  const float* Ws_f = (const float*)d_in[5];
  const float* b_f  = (const float*)d_in[6];
  const float* Us_f = (const float*)d_in[7];
  const float* Uh_f = (const float*)d_in[8];
  const float* bs_f = (const float*)d_in[9];
  const float* Wx_r = (const float*)d_in[10];
  const float* Wh_r = (const float*)d_in[11];
  const float* Ws_r = (const float*)d_in[12];
  const float* b_r  = (const float*)d_in[13];
  const float* Us_r = (const float*)d_in[14];
  const float* Uh_r = (const float*)d_in[15];
  const float* bs_r = (const float*)d_in[16];
  float* out = (float*)d_out;
  uint32_t* ws = (uint32_t*)d_ws;

  const size_t XZ_WORDS = (size_t)2 * SS * H4 * BB / 2;   // 16777216 words (bf16 xz)
  const size_t FLAG_WORDS = 512;
  const size_t BUF_ULL = 16384;                            // h+s exchange buffers
  const size_t need = (XZ_WORDS + FLAG_WORDS) * 4 + BUF_ULL * 8;

  if (ws_size >= need) {
    unsigned short* xz = (unsigned short*)ws;
    uint32_t* flags = ws + XZ_WORDS;
    unsigned long long* bufs = (unsigned long long*)(ws + XZ_WORDS + FLAG_WORDS);
    zero_words<<<dim3(1), dim3(512), 0, stream>>>(flags, (int)FLAG_WORDS);
    xz_prepass<<<dim3(256), dim3(512), 0, stream>>>(x, Wx_f, b_f, Wx_r, b_r, xz);
    slstm_fast2<<<dim3(16), dim3(NTHR), 0, stream>>>(
        mask, Wh_f, Ws_f, Us_f, Uh_f, bs_f,
        Wh_r, Ws_r, Us_r, Uh_r, bs_r, xz, out, flags, bufs);
  } else {
    init_flags<<<dim3(4), dim3(256), 0, stream>>>(ws);
    slstm_persistent<<<dim3(NWG), dim3(NTHR), 0, stream>>>(
        x, mask, Wx_f, Wh_f, Ws_f, b_f, Us_f, Uh_f, bs_f,
        Wx_r, Wh_r, Ws_r, b_r, Us_r, Uh_r, bs_r, out, ws);
  }
}